// Round 14
// baseline (284.374 us; speedup 1.0000x reference)
//
#include <hip/hip_runtime.h>
#include <hip/hip_bf16.h>
#include <stdint.h>

#define THREADS 256

typedef unsigned short u16;
typedef __attribute__((ext_vector_type(8))) short bf16x8;
typedef __attribute__((ext_vector_type(4))) float f32x4;

// native fp32 -> bf16 (compiler emits v_cvt_pk_bf16_f32 for pairs; HW RNE)
__device__ inline u16 f2bf(float x) {
    __bf16 b = (__bf16)x;
    return __builtin_bit_cast(u16, b);
}
__device__ inline float bf2f(u16 h) { return __uint_as_float(((unsigned)h) << 16); }

// lane^1 exchange via DPP quad_perm(1,0,3,2) -- pure VALU, no LDS pipe
__device__ inline float dpp_xor1(float v) {
    int r = __builtin_amdgcn_mov_dpp(__float_as_int(v), 0xB1, 0xF, 0xF, true);
    return __int_as_float(r);
}

__device__ inline void load_lds16(const void* g, void* l) {
    __builtin_amdgcn_global_load_lds(
        (const __attribute__((address_space(1))) unsigned int*)g,
        (__attribute__((address_space(3))) unsigned int*)l, 16, 0, 0);
}

// ---------------------------------------------------------------------------
// Kernel 0: pre-permute w1 AND w2 into per-lane MFMA A-fragments (split bf16).
// ---------------------------------------------------------------------------
__global__ __launch_bounds__(256) void prep_w_kernel(
    const float* __restrict__ w1, const float* __restrict__ w2,
    u16* __restrict__ w1t, u16* __restrict__ w2t)
{
    if (blockIdx.x < 8) {
        int idx = blockIdx.x * 256 + threadIdx.x;   // 0..2047
        int j     = idx & 7;
        int lane  = (idx >> 3) & 63;
        int mt    = (idx >> 9) & 1;
        int plane = (idx >> 10) & 1;
        int oc = mt * 16 + (lane & 15);
        int k = (lane >> 4) * 8 + j;
        float v = 0.0f;
        if (k < 27) { int ic = k / 9, tap = k - ic * 9; v = w1[oc * 27 + ic * 9 + tap]; }
        u16 hb = f2bf(v);
        w1t[idx] = plane ? f2bf(v - bf2f(hb)) : hb;
    } else {
        int idx = (blockIdx.x - 8) * 256 + threadIdx.x;   // 0..36863
        int j     = idx & 7;
        int lane  = (idx >> 3) & 63;
        int mt    = (idx >> 9) & 3;
        int plane = (idx >> 11) & 1;
        int tap   = idx >> 12;                      // 0..8
        int oc = mt * 16 + (lane & 15);
        int ic = (lane >> 4) * 8 + j;
        float v = w2[(size_t)oc * 288 + ic * 9 + tap];
        u16 hb = f2bf(v);
        w2t[idx] = plane ? f2bf(v - bf2f(hb)) : hb;
    }
}

// ---------------------------------------------------------------------------
// Kernel 1: fused conv1(split-bf16 MFMA, tap-packed K=32) +
//           conv2(split-bf16 MFMA, per-tap K=32) + pools -> f
// One image per block (blocks 0..4095), 256 threads (4 waves), 3 blocks/CU.
// Blocks 4096..5095: centroid bf16-split + squared-norm prep.
// ---------------------------------------------------------------------------
#define XSN (3 * 34 * 34)   // 3468

__global__ __launch_bounds__(256, 3) void conv_fused_kernel(
    const float* __restrict__ x,
    const u16* __restrict__ w1t, const float* __restrict__ b1,
    const u16* __restrict__ w2t, const float* __restrict__ b2,
    u16* __restrict__ f_hi, u16* __restrict__ f_lo,
    const float* __restrict__ cent, u16* __restrict__ c_hi,
    u16* __restrict__ c_lo, float* __restrict__ c2)
{
    const int tid = threadIdx.x;
    const int b = blockIdx.x;

    if (b >= 4096) {
        // ---- centroid prep path (1000 blocks) ----
        __shared__ float wsum[4];
        const int n = b - 4096;
        const size_t base = (size_t)n * 4096;
        float s = 0.0f;
        #pragma unroll
        for (int q = 0; q < 4; ++q) {
            int e = (tid + q * 256) * 4;
            float4 v = *(const float4*)(cent + base + e);
            s = fmaf(v.x, v.x, s); s = fmaf(v.y, v.y, s);
            s = fmaf(v.z, v.z, s); s = fmaf(v.w, v.w, s);
            ushort4 h, l;
            h.x = f2bf(v.x); l.x = f2bf(v.x - bf2f(h.x));
            h.y = f2bf(v.y); l.y = f2bf(v.y - bf2f(h.y));
            h.z = f2bf(v.z); l.z = f2bf(v.z - bf2f(h.z));
            h.w = f2bf(v.w); l.w = f2bf(v.w - bf2f(h.w));
            *(ushort4*)(c_hi + base + e) = h;
            *(ushort4*)(c_lo + base + e) = l;
        }
        #pragma unroll
        for (int off = 32; off >= 1; off >>= 1) s += __shfl_down(s, off, 64);
        int lane = tid & 63, wv = tid >> 6;
        if (lane == 0) wsum[wv] = s;
        __syncthreads();
        if (tid == 0) c2[n] = wsum[0] + wsum[1] + wsum[2] + wsum[3];
        return;
    }

    __shared__ __align__(16) unsigned xsi[XSN];         // padded image {hi,lo} (13.9 KB)
    __shared__ __align__(16) u16 h1hi[16 * 16 * 32];    // [y][x][ic] bf16 hi (16.4 KB)
    __shared__ __align__(16) u16 h1lo[16 * 16 * 32];    // [y][x][ic] bf16 lo (16.4 KB)

    const int lane = tid & 63;
    const int li = lane & 15, ls = lane >> 4;
    const int wv = tid >> 6;
    __builtin_assume(li >= 0 && li < 16);
    __builtin_assume(ls >= 0 && ls < 4);
    __builtin_assume(wv >= 0 && wv < 4);

    // phase A: zero xsi (halo must be 0)
    for (int i = tid; i < XSN; i += THREADS) xsi[i] = 0u;
    __syncthreads();

    // phase B: load image interior, split to bf16 hi/lo ONCE (interleaved)
    const float* xb = x + (size_t)b * 3072;
    #pragma unroll
    for (int q = 0; q < 3; ++q) {
        int idx = tid + q * THREADS;      // 0..767
        int ic  = idx >> 8;
        int rem = idx & 255;
        int y   = rem >> 3;
        int x4  = (rem & 7) << 2;
        float4 v = *(const float4*)(xb + ic * 1024 + y * 32 + x4);
        int base = ic * 1156 + (1 + y) * 34 + 1 + x4;
        float vv[4] = {v.x, v.y, v.z, v.w};
        #pragma unroll
        for (int e = 0; e < 4; ++e) {
            u16 hb = f2bf(vv[e]);
            u16 lb = f2bf(vv[e] - bf2f(hb));
            xsi[base + e] = (unsigned)hb | ((unsigned)lb << 16);
        }
    }
    __syncthreads();

    // phase C: conv1 via MFMA (tap-packed K=32, 3-term split) + pool -> h1
    {
        bf16x8 aH1[2], aL1[2];
        #pragma unroll
        for (int mt = 0; mt < 2; ++mt) {
            aH1[mt] = *(const bf16x8*)(w1t + (size_t)((0 * 2 + mt) * 64 + lane) * 8);
            aL1[mt] = *(const bf16x8*)(w1t + (size_t)((1 * 2 + mt) * 64 + lane) * 8);
        }
        int koffc[8];
        #pragma unroll
        for (int j = 0; j < 8; ++j) {
            int k = ls * 8 + j;
            int kc = (k < 27) ? k : 0;
            int ic = kc / 9, tap = kc - ic * 9;
            int ky = tap / 3, kx = tap - ky * 3;
            koffc[j] = ic * 1156 + ky * 34 + kx;
        }
        float b1v[2][4];
        #pragma unroll
        for (int mt = 0; mt < 2; ++mt)
            #pragma unroll
            for (int reg = 0; reg < 4; ++reg)
                b1v[mt][reg] = b1[16 * mt + 4 * ls + reg];

        #pragma unroll
        for (int q = 0; q < 4; ++q) {           // row-pair quad
            f32x4 acc[4][2];
            #pragma unroll
            for (int s = 0; s < 4; ++s)
                #pragma unroll
                for (int mt = 0; mt < 2; ++mt)
                    acc[s][mt] = (f32x4){b1v[mt][0], b1v[mt][1], b1v[mt][2], b1v[mt][3]};

            #pragma unroll
            for (int s = 0; s < 4; ++s) {       // s: (row-lsb, col-half)
                int y = 8 * wv + 2 * q + (s >> 1);
                int xcol = 16 * (s & 1) + li;
                int base = y * 34 + xcol;
                bf16x8 bH, bL;
                #pragma unroll
                for (int j = 0; j < 8; ++j) {
                    unsigned dw = xsi[base + koffc[j]];
                    bH[j] = (short)(u16)(dw & 0xffffu);
                    bL[j] = (short)(u16)(dw >> 16);
                }
                #pragma unroll
                for (int mt = 0; mt < 2; ++mt) {
                    acc[s][mt] = __builtin_amdgcn_mfma_f32_16x16x32_bf16(aH1[mt], bH, acc[s][mt], 0, 0, 0);
                    acc[s][mt] = __builtin_amdgcn_mfma_f32_16x16x32_bf16(aH1[mt], bL, acc[s][mt], 0, 0, 0);
                    acc[s][mt] = __builtin_amdgcn_mfma_f32_16x16x32_bf16(aL1[mt], bH, acc[s][mt], 0, 0, 0);
                }
            }
            // pool quad: x via DPP lane^1, y via acc[h] vs acc[h+2]; write h1
            int py = 4 * wv + q;
            #pragma unroll
            for (int h = 0; h < 2; ++h) {
                #pragma unroll
                for (int mt = 0; mt < 2; ++mt) {
                    ushort4 pH, pL;
                    #pragma unroll
                    for (int reg = 0; reg < 4; ++reg) {
                        float v0 = acc[h][mt][reg];
                        float v1 = acc[h + 2][mt][reg];
                        float m0 = fmaxf(v0, dpp_xor1(v0));
                        float m1 = fmaxf(v1, dpp_xor1(v1));
                        float v = fmaxf(fmaxf(m0, m1), 0.0f);   // bias already in acc
                        u16 hb = f2bf(v);
                        ((u16*)&pH)[reg] = hb;
                        ((u16*)&pL)[reg] = f2bf(v - bf2f(hb));
                    }
                    if ((li & 1) == 0) {
                        int px = (li >> 1) + 8 * h;
                        int ib = 2 * mt + (ls >> 1);     // logical slot (oc>>3)
                        int byte = (py * 16 + px) * 64 + ((ib ^ ((px >> 1) & 3)) << 4) + (ls & 1) * 8;
                        *(ushort4*)((char*)h1hi + byte) = pH;
                        *(ushort4*)((char*)h1lo + byte) = pL;
                    }
                }
            }
        }
    }
    __syncthreads();

    // phase D: conv2 via split-bf16 MFMA (3-term), kx-outer with row caching
    {
        const bf16x8 zf = {0, 0, 0, 0, 0, 0, 0, 0};

        float b2v[4][4];
        #pragma unroll
        for (int mt = 0; mt < 4; ++mt)
            #pragma unroll
            for (int reg = 0; reg < 4; ++reg)
                b2v[mt][reg] = b2[mt * 16 + ls * 4 + reg];

        f32x4 acc[4][4];                    // [mt][ntl], bias-initialized
        #pragma unroll
        for (int mt = 0; mt < 4; ++mt)
            #pragma unroll
            for (int ntl = 0; ntl < 4; ++ntl)
                acc[mt][ntl] = (f32x4){b2v[mt][0], b2v[mt][1], b2v[mt][2], b2v[mt][3]};

        #pragma unroll
        for (int kx = 0; kx < 3; ++kx) {
            int xg = li + kx - 1;                 // -1..16
            bool xo = (unsigned)xg > 15u;
            int xc = min(max(xg, 0), 15);
            int slotb = (ls ^ ((xc >> 1) & 3)) << 4;

            // cache interior rows d = 0..4 (yg = 4wv+d), used up to 3x each
            bf16x8 cH[5], cL[5];
            #pragma unroll
            for (int d = 0; d < 5; ++d) {
                int yg = 4 * wv + d;
                if (yg <= 15) {
                    int byte = (yg * 16 + xc) * 64 + slotb;
                    bf16x8 h = *(const bf16x8*)((const char*)h1hi + byte);
                    bf16x8 l = *(const bf16x8*)((const char*)h1lo + byte);
                    cH[d] = xo ? zf : h;
                    cL[d] = xo ? zf : l;
                } else { cH[d] = zf; cL[d] = zf; }
            }

            #pragma unroll
            for (int ky = 0; ky < 3; ++ky) {
                const int tap = ky * 3 + kx;
                bf16x8 aH[4], aL[4];
                #pragma unroll
                for (int mt = 0; mt < 4; ++mt) {
                    aH[mt] = *(const bf16x8*)(w2t + (size_t)(tap * 4096 + mt * 512 + lane * 8));
                    aL[mt] = *(const bf16x8*)(w2t + (size_t)(tap * 4096 + 2048 + mt * 512 + lane * 8));
                }
                #pragma unroll
                for (int ntl = 0; ntl < 4; ++ntl) {
                    int d = ntl + ky - 1;         // -1..5
                    int yg = 4 * wv + d;
                    if ((unsigned)yg > 15u) continue;   // zero-row tap (uniform)
                    bf16x8 bH, bL;
                    if (d == -1 || d == 5) {      // edge rows: on-demand read
                        int byte = (yg * 16 + xc) * 64 + slotb;
                        bH = *(const bf16x8*)((const char*)h1hi + byte);
                        bL = *(const bf16x8*)((const char*)h1lo + byte);
                        if (xo) { bH = zf; bL = zf; }
                    } else {
                        bH = cH[d]; bL = cL[d];
                    }
                    #pragma unroll
                    for (int mt = 0; mt < 4; ++mt) {
                        acc[mt][ntl] = __builtin_amdgcn_mfma_f32_16x16x32_bf16(aH[mt], bH, acc[mt][ntl], 0, 0, 0);
                        acc[mt][ntl] = __builtin_amdgcn_mfma_f32_16x16x32_bf16(aH[mt], bL, acc[mt][ntl], 0, 0, 0);
                        acc[mt][ntl] = __builtin_amdgcn_mfma_f32_16x16x32_bf16(aL[mt], bH, acc[mt][ntl], 0, 0, 0);
                    }
                }
            }
        }

        // epilogue: 2x2 maxpool (DPP lane^1), relu, split-store f
        const size_t fbase = (size_t)b * 4096;
        #pragma unroll
        for (int mt = 0; mt < 4; ++mt) {
            #pragma unroll
            for (int reg = 0; reg < 4; ++reg) {
                int oc = mt * 16 + ls * 4 + reg;
                #pragma unroll
                for (int p = 0; p < 2; ++p) {
                    float v0 = acc[mt][2 * p + 0][reg];
                    float v1 = acc[mt][2 * p + 1][reg];
                    float x0 = fmaxf(v0, dpp_xor1(v0));
                    float x1 = fmaxf(v1, dpp_xor1(v1));
                    float v = fmaxf(fmaxf(x0, x1), 0.0f);   // bias already in acc
                    if ((li & 1) == 0) {
                        int py = 2 * wv + p, px = li >> 1;
                        u16 hb = f2bf(v);
                        u16 lb = f2bf(v - bf2f(hb));
                        size_t o = fbase + (size_t)oc * 64 + py * 8 + px;
                        f_hi[o] = hb;
                        f_lo[o] = lb;
                    }
                }
            }
        }
    }
}

// ---------------------------------------------------------------------------
// Kernel 2: split-bf16 MFMA GEMM (f . cent^T, 3-term, 128x64 tile, grid 512)
// + fused argmin epilogue. XCD-disjoint f mapping (id%8 round-robin):
//   xcd = id&7; g = id>>3; mb = xcd*4 + (g&3); nb = g>>2   (bijective)
// 2-phase double-buffered staging: STAGE(t+1) issued BEFORE compute(t);
// the per-iter __syncthreads (implicit vmcnt(0)) makes it race-safe.
// Loads are L2-resident under this mapping, so the prefetch burst queues in
// L2, not HBM (the r10 failure mode at 300 MB HBM traffic no longer applies).
// ---------------------------------------------------------------------------
#define GBM 128
#define GBN 64
#define GBK 32

__global__ __launch_bounds__(256, 2) void gemm_argmin_mfma(
    const u16* __restrict__ f_hi, const u16* __restrict__ f_lo,
    const u16* __restrict__ c_hi, const u16* __restrict__ c_lo,
    const float* __restrict__ c2, unsigned long long* __restrict__ packed)
{
    __shared__ __align__(16) u16 Ah[2][GBM * GBK];
    __shared__ __align__(16) u16 Al[2][GBM * GBK];
    __shared__ __align__(16) u16 Bh[2][GBN * GBK];
    __shared__ __align__(16) u16 Bl[2][GBN * GBK];
    __shared__ unsigned long long red[GBM];

    const int tid = threadIdx.x;
    const int id = blockIdx.x;
    const int xcd = id & 7;
    const int g = id >> 3;
    const int mb = xcd * 4 + (g & 3);   // 4 disjoint m-panels per XCD
    const int nb = g >> 2;              // all 16 n-panels per XCD
    const int m0 = mb * GBM;
    const int n0 = nb * GBN;

    const int lane = tid & 63;
    const int wid  = tid >> 6;
    const int wm = wid >> 1, wn = wid & 1;
    const int li = lane & 15;
    const int ls = lane >> 4;
    const int swz = (li >> 1) & 3;
    const int rslot = (ls ^ swz) << 4;   // byte offset of this lane's 16B slot

    f32x4 acc[4][2];
    #pragma unroll
    for (int i = 0; i < 4; ++i)
        #pragma unroll
        for (int j = 0; j < 2; ++j) acc[i][j] = (f32x4){0.f, 0.f, 0.f, 0.f};

    // staging: linear LDS dest, swizzle applied on global source (m173 pattern)
    auto STAGE = [&](int buf, int k0) {
        #pragma unroll
        for (int q = 0; q < 2; ++q) {
            int idx = tid + q * 256;          // 0..511
            int row = idx >> 2, slot = idx & 3;
            int kg = k0 + ((slot ^ ((row >> 1) & 3)) << 3);
            size_t goff = (size_t)(m0 + row) * 4096 + kg;
            load_lds16(f_hi + goff, &Ah[buf][idx * 8]);
            load_lds16(f_lo + goff, &Al[buf][idx * 8]);
        }
        {
            int idx = tid;                    // 0..255
            int row = idx >> 2, slot = idx & 3;
            int kg = k0 + ((slot ^ ((row >> 1) & 3)) << 3);
            size_t goff = (size_t)(n0 + row) * 4096 + kg;
            load_lds16(c_hi + goff, &Bh[buf][idx * 8]);
            load_lds16(c_lo + goff, &Bl[buf][idx * 8]);
        }
    };

    auto COMPUTE = [&](int buf) {
        bf16x8 ah[4], al[4], bh[2], bl[2];
        #pragma unroll
        for (int mt = 0; mt < 4; ++mt) {
            int r = wm * 64 + mt * 16 + li;
            int byte = r * 64 + rslot;
            ah[mt] = *(const bf16x8*)((const char*)&Ah[buf][0] + byte);
            al[mt] = *(const bf16x8*)((const char*)&Al[buf][0] + byte);
        }
        #pragma unroll
        for (int nt = 0; nt < 2; ++nt) {
            int r = wn * 32 + nt * 16 + li;
            int byte = r * 64 + rslot;
            bh[nt] = *(const bf16x8*)((const char*)&Bh[buf][0] + byte);
            bl[nt] = *(const bf16x8*)((const char*)&Bl[buf][0] + byte);
        }
        #pragma unroll
        for (int mt = 0; mt < 4; ++mt)
            #pragma unroll
            for (int nt = 0; nt < 2; ++nt) {
                acc[mt][nt] = __builtin_amdgcn_mfma_f32_16x16x32_bf16(ah[mt], bh[nt], acc[mt][nt], 0, 0, 0);
                acc[mt][nt] = __builtin_amdgcn_mfma_f32_16x16x32_bf16(ah[mt], bl[nt], acc[mt][nt], 0, 0, 0);
                acc[mt][nt] = __builtin_amdgcn_mfma_f32_16x16x32_bf16(al[mt], bh[nt], acc[mt][nt], 0, 0, 0);
            }
    };

    // prologue: stage tile 0, init reduction slots
    STAGE(0, 0);
    if (tid < GBM) red[tid] = ~0ULL;
    __syncthreads();                      // tile 0 resident

    int cur = 0;
    for (int t = 0; t < 127; ++t) {
        STAGE(cur ^ 1, (t + 1) * GBK);    // issue next tile (in flight during compute)
        COMPUTE(cur);
        __syncthreads();                  // drains vmcnt -> next tile resident
        cur ^= 1;
    }
    COMPUTE(cur);                         // last tile (no prefetch)

    // epilogue: argmin of (c2[n] - 2*dot). C/D: col=lane&15, row=(lane>>4)*4+reg.
    #pragma unroll
    for (int mt = 0; mt < 4; ++mt) {
        #pragma unroll
        for (int reg = 0; reg < 4; ++reg) {
            unsigned long long best = ~0ULL;
            #pragma unroll
            for (int nt = 0; nt < 2; ++nt) {
                int n = n0 + wn * 32 + nt * 16 + li;
                if (n < 1000) {
                    float v = c2[n] - 2.0f * acc[mt][nt][reg];
                    unsigned bi = __float_as_uint(v);
                    bi = (bi & 0x80000000u) ? ~bi : (bi | 0x80000000u);
                    unsigned long long key = ((unsigned long long)bi << 32) | (unsigned)n;
                    if (key < best) best = key;
                }
            }
            #pragma unroll
            for (int d = 1; d < 16; d <<= 1) {
                unsigned long long o = __shfl_xor(best, d, 64);
                if (o < best) best = o;
            }
            if (li == 0) {
                int lr = wm * 64 + mt * 16 + ls * 4 + reg;
                atomicMin(&red[lr], best);
            }
        }
    }
    __syncthreads();
    if (tid < GBM) atomicMin(&packed[m0 + tid], red[tid]);
}

// ---------------------------------------------------------------------------
// Kernel 3: unpack argmin index
// ---------------------------------------------------------------------------
__global__ __launch_bounds__(256) void extract_kernel(
    const unsigned long long* __restrict__ packed, int* __restrict__ out)
{
    int i = blockIdx.x * 256 + threadIdx.x;
    out[i] = (int)(unsigned)(packed[i] & 0xFFFFFFFFull);
}

// ---------------------------------------------------------------------------
extern "C" void kernel_launch(void* const* d_in, const int* in_sizes, int n_in,
                              void* d_out, int out_size, void* d_ws, size_t ws_size,
                              hipStream_t stream)
{
    const float* x    = (const float*)d_in[0];
    const float* w1   = (const float*)d_in[1];
    const float* b1   = (const float*)d_in[2];
    const float* w2   = (const float*)d_in[3];
    const float* b2   = (const float*)d_in[4];
    const float* cent = (const float*)d_in[5];
    int* out = (int*)d_out;

    char* ws = (char*)d_ws;
    u16* f_hi = (u16*)(ws);                          // 4096*4096*2 = 33554432
    u16* f_lo = (u16*)(ws + 33554432);               // 33554432
    u16* c_hi = (u16*)(ws + 67108864);               // 1024*4096*2 = 8388608
    u16* c_lo = (u16*)(ws + 75497472);               // 8388608
    float* c2 = (float*)(ws + 83886080);             // 4096
    unsigned long long* packed =
        (unsigned long long*)(ws + 83890176);        // 32768
    u16* w1t = (u16*)(ws + 83922944);                // 4096
    u16* w2t = (u16*)(ws + 83927040);                // 73728 (dedicated)

    hipMemsetAsync(packed, 0xFF, 4096 * sizeof(unsigned long long), stream);
    prep_w_kernel<<<152, 256, 0, stream>>>(w1, w2, w1t, w2t);
    conv_fused_kernel<<<5096, 256, 0, stream>>>(x, w1t, b1, w2t, b2, f_hi, f_lo,
                                                cent, c_hi, c_lo, c2);
    gemm_argmin_mfma<<<512, 256, 0, stream>>>(f_hi, f_lo, c_hi, c_lo, c2, packed);
    extract_kernel<<<16, 256, 0, stream>>>(packed, out);
}

// Round 15
// 222.127 us; speedup vs baseline: 1.2802x; 1.2802x over previous
//
#include <hip/hip_runtime.h>
#include <hip/hip_bf16.h>
#include <stdint.h>

#define THREADS 256

typedef unsigned short u16;
typedef __attribute__((ext_vector_type(8))) short bf16x8;
typedef __attribute__((ext_vector_type(4))) float f32x4;

// native fp32 -> bf16 (compiler emits v_cvt_pk_bf16_f32 for pairs; HW RNE)
__device__ inline u16 f2bf(float x) {
    __bf16 b = (__bf16)x;
    return __builtin_bit_cast(u16, b);
}
__device__ inline float bf2f(u16 h) { return __uint_as_float(((unsigned)h) << 16); }

// lane^1 exchange via DPP quad_perm(1,0,3,2) -- pure VALU, no LDS pipe
__device__ inline float dpp_xor1(float v) {
    int r = __builtin_amdgcn_mov_dpp(__float_as_int(v), 0xB1, 0xF, 0xF, true);
    return __int_as_float(r);
}

__device__ inline void load_lds16(const void* g, void* l) {
    __builtin_amdgcn_global_load_lds(
        (const __attribute__((address_space(1))) unsigned int*)g,
        (__attribute__((address_space(3))) unsigned int*)l, 16, 0, 0);
}

// ---------------------------------------------------------------------------
// Kernel 0: pre-permute w1 AND w2 into per-lane MFMA A-fragments (split bf16).
// ---------------------------------------------------------------------------
__global__ __launch_bounds__(256) void prep_w_kernel(
    const float* __restrict__ w1, const float* __restrict__ w2,
    u16* __restrict__ w1t, u16* __restrict__ w2t)
{
    if (blockIdx.x < 8) {
        int idx = blockIdx.x * 256 + threadIdx.x;   // 0..2047
        int j     = idx & 7;
        int lane  = (idx >> 3) & 63;
        int mt    = (idx >> 9) & 1;
        int plane = (idx >> 10) & 1;
        int oc = mt * 16 + (lane & 15);
        int k = (lane >> 4) * 8 + j;
        float v = 0.0f;
        if (k < 27) { int ic = k / 9, tap = k - ic * 9; v = w1[oc * 27 + ic * 9 + tap]; }
        u16 hb = f2bf(v);
        w1t[idx] = plane ? f2bf(v - bf2f(hb)) : hb;
    } else {
        int idx = (blockIdx.x - 8) * 256 + threadIdx.x;   // 0..36863
        int j     = idx & 7;
        int lane  = (idx >> 3) & 63;
        int mt    = (idx >> 9) & 3;
        int plane = (idx >> 11) & 1;
        int tap   = idx >> 12;                      // 0..8
        int oc = mt * 16 + (lane & 15);
        int ic = (lane >> 4) * 8 + j;
        float v = w2[(size_t)oc * 288 + ic * 9 + tap];
        u16 hb = f2bf(v);
        w2t[idx] = plane ? f2bf(v - bf2f(hb)) : hb;
    }
}

// ---------------------------------------------------------------------------
// Kernel 1: fused conv1(split-bf16 MFMA, tap-packed K=32) +
//           conv2(split-bf16 MFMA, per-tap K=32) + pools -> f
// One image per block (blocks 0..4095), 256 threads (4 waves), 3 blocks/CU.
// Blocks 4096..5095: centroid bf16-split + squared-norm prep.
// ---------------------------------------------------------------------------
#define XSN (3 * 34 * 34)   // 3468

__global__ __launch_bounds__(256, 3) void conv_fused_kernel(
    const float* __restrict__ x,
    const u16* __restrict__ w1t, const float* __restrict__ b1,
    const u16* __restrict__ w2t, const float* __restrict__ b2,
    u16* __restrict__ f_hi, u16* __restrict__ f_lo,
    const float* __restrict__ cent, u16* __restrict__ c_hi,
    u16* __restrict__ c_lo, float* __restrict__ c2)
{
    const int tid = threadIdx.x;
    const int b = blockIdx.x;

    if (b >= 4096) {
        // ---- centroid prep path (1000 blocks) ----
        __shared__ float wsum[4];
        const int n = b - 4096;
        const size_t base = (size_t)n * 4096;
        float s = 0.0f;
        #pragma unroll
        for (int q = 0; q < 4; ++q) {
            int e = (tid + q * 256) * 4;
            float4 v = *(const float4*)(cent + base + e);
            s = fmaf(v.x, v.x, s); s = fmaf(v.y, v.y, s);
            s = fmaf(v.z, v.z, s); s = fmaf(v.w, v.w, s);
            ushort4 h, l;
            h.x = f2bf(v.x); l.x = f2bf(v.x - bf2f(h.x));
            h.y = f2bf(v.y); l.y = f2bf(v.y - bf2f(h.y));
            h.z = f2bf(v.z); l.z = f2bf(v.z - bf2f(h.z));
            h.w = f2bf(v.w); l.w = f2bf(v.w - bf2f(h.w));
            *(ushort4*)(c_hi + base + e) = h;
            *(ushort4*)(c_lo + base + e) = l;
        }
        #pragma unroll
        for (int off = 32; off >= 1; off >>= 1) s += __shfl_down(s, off, 64);
        int lane = tid & 63, wv = tid >> 6;
        if (lane == 0) wsum[wv] = s;
        __syncthreads();
        if (tid == 0) c2[n] = wsum[0] + wsum[1] + wsum[2] + wsum[3];
        return;
    }

    __shared__ __align__(16) unsigned xsi[XSN];         // padded image {hi,lo} (13.9 KB)
    __shared__ __align__(16) u16 h1hi[16 * 16 * 32];    // [y][x][ic] bf16 hi (16.4 KB)
    __shared__ __align__(16) u16 h1lo[16 * 16 * 32];    // [y][x][ic] bf16 lo (16.4 KB)

    const int lane = tid & 63;
    const int li = lane & 15, ls = lane >> 4;
    const int wv = tid >> 6;
    __builtin_assume(li >= 0 && li < 16);
    __builtin_assume(ls >= 0 && ls < 4);
    __builtin_assume(wv >= 0 && wv < 4);

    // phase A: zero xsi (halo must be 0)
    for (int i = tid; i < XSN; i += THREADS) xsi[i] = 0u;
    __syncthreads();

    // phase B: load image interior, split to bf16 hi/lo ONCE (interleaved)
    const float* xb = x + (size_t)b * 3072;
    #pragma unroll
    for (int q = 0; q < 3; ++q) {
        int idx = tid + q * THREADS;      // 0..767
        int ic  = idx >> 8;
        int rem = idx & 255;
        int y   = rem >> 3;
        int x4  = (rem & 7) << 2;
        float4 v = *(const float4*)(xb + ic * 1024 + y * 32 + x4);
        int base = ic * 1156 + (1 + y) * 34 + 1 + x4;
        float vv[4] = {v.x, v.y, v.z, v.w};
        #pragma unroll
        for (int e = 0; e < 4; ++e) {
            u16 hb = f2bf(vv[e]);
            u16 lb = f2bf(vv[e] - bf2f(hb));
            xsi[base + e] = (unsigned)hb | ((unsigned)lb << 16);
        }
    }
    __syncthreads();

    // phase C: conv1 via MFMA (tap-packed K=32, 3-term split) + pool -> h1
    {
        bf16x8 aH1[2], aL1[2];
        #pragma unroll
        for (int mt = 0; mt < 2; ++mt) {
            aH1[mt] = *(const bf16x8*)(w1t + (size_t)((0 * 2 + mt) * 64 + lane) * 8);
            aL1[mt] = *(const bf16x8*)(w1t + (size_t)((1 * 2 + mt) * 64 + lane) * 8);
        }
        int koffc[8];
        #pragma unroll
        for (int j = 0; j < 8; ++j) {
            int k = ls * 8 + j;
            int kc = (k < 27) ? k : 0;
            int ic = kc / 9, tap = kc - ic * 9;
            int ky = tap / 3, kx = tap - ky * 3;
            koffc[j] = ic * 1156 + ky * 34 + kx;
        }
        float b1v[2][4];
        #pragma unroll
        for (int mt = 0; mt < 2; ++mt)
            #pragma unroll
            for (int reg = 0; reg < 4; ++reg)
                b1v[mt][reg] = b1[16 * mt + 4 * ls + reg];

        #pragma unroll
        for (int q = 0; q < 4; ++q) {           // row-pair quad
            f32x4 acc[4][2];
            #pragma unroll
            for (int s = 0; s < 4; ++s)
                #pragma unroll
                for (int mt = 0; mt < 2; ++mt)
                    acc[s][mt] = (f32x4){b1v[mt][0], b1v[mt][1], b1v[mt][2], b1v[mt][3]};

            #pragma unroll
            for (int s = 0; s < 4; ++s) {       // s: (row-lsb, col-half)
                int y = 8 * wv + 2 * q + (s >> 1);
                int xcol = 16 * (s & 1) + li;
                int base = y * 34 + xcol;
                bf16x8 bH, bL;
                #pragma unroll
                for (int j = 0; j < 8; ++j) {
                    unsigned dw = xsi[base + koffc[j]];
                    bH[j] = (short)(u16)(dw & 0xffffu);
                    bL[j] = (short)(u16)(dw >> 16);
                }
                #pragma unroll
                for (int mt = 0; mt < 2; ++mt) {
                    acc[s][mt] = __builtin_amdgcn_mfma_f32_16x16x32_bf16(aH1[mt], bH, acc[s][mt], 0, 0, 0);
                    acc[s][mt] = __builtin_amdgcn_mfma_f32_16x16x32_bf16(aH1[mt], bL, acc[s][mt], 0, 0, 0);
                    acc[s][mt] = __builtin_amdgcn_mfma_f32_16x16x32_bf16(aL1[mt], bH, acc[s][mt], 0, 0, 0);
                }
            }
            // pool quad: x via DPP lane^1, y via acc[h] vs acc[h+2]; write h1
            int py = 4 * wv + q;
            #pragma unroll
            for (int h = 0; h < 2; ++h) {
                #pragma unroll
                for (int mt = 0; mt < 2; ++mt) {
                    ushort4 pH, pL;
                    #pragma unroll
                    for (int reg = 0; reg < 4; ++reg) {
                        float v0 = acc[h][mt][reg];
                        float v1 = acc[h + 2][mt][reg];
                        float m0 = fmaxf(v0, dpp_xor1(v0));
                        float m1 = fmaxf(v1, dpp_xor1(v1));
                        float v = fmaxf(fmaxf(m0, m1), 0.0f);   // bias already in acc
                        u16 hb = f2bf(v);
                        ((u16*)&pH)[reg] = hb;
                        ((u16*)&pL)[reg] = f2bf(v - bf2f(hb));
                    }
                    if ((li & 1) == 0) {
                        int px = (li >> 1) + 8 * h;
                        int ib = 2 * mt + (ls >> 1);     // logical slot (oc>>3)
                        int byte = (py * 16 + px) * 64 + ((ib ^ ((px >> 1) & 3)) << 4) + (ls & 1) * 8;
                        *(ushort4*)((char*)h1hi + byte) = pH;
                        *(ushort4*)((char*)h1lo + byte) = pL;
                    }
                }
            }
        }
    }
    __syncthreads();

    // phase D: conv2 via split-bf16 MFMA (3-term), kx-outer with row caching
    {
        const bf16x8 zf = {0, 0, 0, 0, 0, 0, 0, 0};

        float b2v[4][4];
        #pragma unroll
        for (int mt = 0; mt < 4; ++mt)
            #pragma unroll
            for (int reg = 0; reg < 4; ++reg)
                b2v[mt][reg] = b2[mt * 16 + ls * 4 + reg];

        f32x4 acc[4][4];                    // [mt][ntl], bias-initialized
        #pragma unroll
        for (int mt = 0; mt < 4; ++mt)
            #pragma unroll
            for (int ntl = 0; ntl < 4; ++ntl)
                acc[mt][ntl] = (f32x4){b2v[mt][0], b2v[mt][1], b2v[mt][2], b2v[mt][3]};

        #pragma unroll
        for (int kx = 0; kx < 3; ++kx) {
            int xg = li + kx - 1;                 // -1..16
            bool xo = (unsigned)xg > 15u;
            int xc = min(max(xg, 0), 15);
            int slotb = (ls ^ ((xc >> 1) & 3)) << 4;

            // cache interior rows d = 0..4 (yg = 4wv+d), used up to 3x each
            bf16x8 cH[5], cL[5];
            #pragma unroll
            for (int d = 0; d < 5; ++d) {
                int yg = 4 * wv + d;
                if (yg <= 15) {
                    int byte = (yg * 16 + xc) * 64 + slotb;
                    bf16x8 h = *(const bf16x8*)((const char*)h1hi + byte);
                    bf16x8 l = *(const bf16x8*)((const char*)h1lo + byte);
                    cH[d] = xo ? zf : h;
                    cL[d] = xo ? zf : l;
                } else { cH[d] = zf; cL[d] = zf; }
            }

            #pragma unroll
            for (int ky = 0; ky < 3; ++ky) {
                const int tap = ky * 3 + kx;
                bf16x8 aH[4], aL[4];
                #pragma unroll
                for (int mt = 0; mt < 4; ++mt) {
                    aH[mt] = *(const bf16x8*)(w2t + (size_t)(tap * 4096 + mt * 512 + lane * 8));
                    aL[mt] = *(const bf16x8*)(w2t + (size_t)(tap * 4096 + 2048 + mt * 512 + lane * 8));
                }
                #pragma unroll
                for (int ntl = 0; ntl < 4; ++ntl) {
                    int d = ntl + ky - 1;         // -1..5
                    int yg = 4 * wv + d;
                    if ((unsigned)yg > 15u) continue;   // zero-row tap (uniform)
                    bf16x8 bH, bL;
                    if (d == -1 || d == 5) {      // edge rows: on-demand read
                        int byte = (yg * 16 + xc) * 64 + slotb;
                        bH = *(const bf16x8*)((const char*)h1hi + byte);
                        bL = *(const bf16x8*)((const char*)h1lo + byte);
                        if (xo) { bH = zf; bL = zf; }
                    } else {
                        bH = cH[d]; bL = cL[d];
                    }
                    #pragma unroll
                    for (int mt = 0; mt < 4; ++mt) {
                        acc[mt][ntl] = __builtin_amdgcn_mfma_f32_16x16x32_bf16(aH[mt], bH, acc[mt][ntl], 0, 0, 0);
                        acc[mt][ntl] = __builtin_amdgcn_mfma_f32_16x16x32_bf16(aH[mt], bL, acc[mt][ntl], 0, 0, 0);
                        acc[mt][ntl] = __builtin_amdgcn_mfma_f32_16x16x32_bf16(aL[mt], bH, acc[mt][ntl], 0, 0, 0);
                    }
                }
            }
        }

        // epilogue: 2x2 maxpool (DPP lane^1), relu, split-store f
        const size_t fbase = (size_t)b * 4096;
        #pragma unroll
        for (int mt = 0; mt < 4; ++mt) {
            #pragma unroll
            for (int reg = 0; reg < 4; ++reg) {
                int oc = mt * 16 + ls * 4 + reg;
                #pragma unroll
                for (int p = 0; p < 2; ++p) {
                    float v0 = acc[mt][2 * p + 0][reg];
                    float v1 = acc[mt][2 * p + 1][reg];
                    float x0 = fmaxf(v0, dpp_xor1(v0));
                    float x1 = fmaxf(v1, dpp_xor1(v1));
                    float v = fmaxf(fmaxf(x0, x1), 0.0f);   // bias already in acc
                    if ((li & 1) == 0) {
                        int py = 2 * wv + p, px = li >> 1;
                        u16 hb = f2bf(v);
                        u16 lb = f2bf(v - bf2f(hb));
                        size_t o = fbase + (size_t)oc * 64 + py * 8 + px;
                        f_hi[o] = hb;
                        f_lo[o] = lb;
                    }
                }
            }
        }
    }
}

// ---------------------------------------------------------------------------
// Kernel 2: split-bf16 MFMA GEMM (f . cent^T, 3-term, 128x64 tile, BK=64,
// grid 512) + fused argmin epilogue. Single-buffer 2-barrier structure
// (dbuf retired: r10/r14 both regressed — barrier drains vmcnt anyway and
// stage-writes contend with ds_reads; cross-block TLP is the overlap source).
// BK=64 halves barrier count; 49 KB LDS -> 3 blocks/CU.
// XCD-disjoint f mapping: xcd=id&7; g=id>>3; mb=xcd*4+(g&3); nb=g>>2.
// Swizzle: 8 slots/row, slot ^= row&7 (involution; 2-way read = free).
// ---------------------------------------------------------------------------
#define GBM 128
#define GBN 64
#define GBK 64

__global__ __launch_bounds__(256, 3) void gemm_argmin_mfma(
    const u16* __restrict__ f_hi, const u16* __restrict__ f_lo,
    const u16* __restrict__ c_hi, const u16* __restrict__ c_lo,
    const float* __restrict__ c2, unsigned long long* __restrict__ packed)
{
    __shared__ __align__(16) u16 Ah[GBM * GBK];   // 16 KB
    __shared__ __align__(16) u16 Al[GBM * GBK];   // 16 KB
    __shared__ __align__(16) u16 Bh[GBN * GBK];   // 8 KB
    __shared__ __align__(16) u16 Bl[GBN * GBK];   // 8 KB
    __shared__ unsigned long long red[GBM];

    const int tid = threadIdx.x;
    const int id = blockIdx.x;
    const int xcd = id & 7;
    const int g = id >> 3;
    const int mb = xcd * 4 + (g & 3);   // 4 disjoint m-panels per XCD
    const int nb = g >> 2;              // all 16 n-panels per XCD
    const int m0 = mb * GBM;
    const int n0 = nb * GBN;

    const int lane = tid & 63;
    const int wid  = tid >> 6;
    const int wm = wid >> 1, wn = wid & 1;
    const int li = lane & 15;
    const int ls = lane >> 4;

    if (tid < GBM) red[tid] = ~0ULL;

    f32x4 acc[4][2];
    #pragma unroll
    for (int i = 0; i < 4; ++i)
        #pragma unroll
        for (int j = 0; j < 2; ++j) acc[i][j] = (f32x4){0.f, 0.f, 0.f, 0.f};

    for (int k0 = 0; k0 < 4096; k0 += GBK) {
        // stage A: 128 rows x 64 k (1024 16B-chunks per plane), swizzled source
        #pragma unroll
        for (int q = 0; q < 4; ++q) {
            int idx = tid + q * 256;          // 0..1023
            int row = idx >> 3, slot = idx & 7;
            int kg = k0 + ((slot ^ (row & 7)) << 3);
            size_t goff = (size_t)(m0 + row) * 4096 + kg;
            load_lds16(f_hi + goff, &Ah[idx * 8]);
            load_lds16(f_lo + goff, &Al[idx * 8]);
        }
        // stage B: 64 rows x 64 k (512 chunks per plane)
        #pragma unroll
        for (int q = 0; q < 2; ++q) {
            int idx = tid + q * 256;          // 0..511
            int row = idx >> 3, slot = idx & 7;
            int kg = k0 + ((slot ^ (row & 7)) << 3);
            size_t goff = (size_t)(n0 + row) * 4096 + kg;
            load_lds16(c_hi + goff, &Bh[idx * 8]);
            load_lds16(c_lo + goff, &Bl[idx * 8]);
        }
        __syncthreads();   // drains vmcnt -> tile resident

        #pragma unroll
        for (int ks = 0; ks < 2; ++ks) {      // two K=32 sub-steps
            const int c = ks * 4 + ls;        // global 16B k-chunk index
            bf16x8 ah[4], al[4], bh[2], bl[2];
            #pragma unroll
            for (int mt = 0; mt < 4; ++mt) {
                int r = wm * 64 + mt * 16 + li;
                int byte = r * 128 + ((c ^ (r & 7)) << 4);
                ah[mt] = *(const bf16x8*)((const char*)Ah + byte);
                al[mt] = *(const bf16x8*)((const char*)Al + byte);
            }
            #pragma unroll
            for (int nt = 0; nt < 2; ++nt) {
                int r = wn * 32 + nt * 16 + li;
                int byte = r * 128 + ((c ^ (r & 7)) << 4);
                bh[nt] = *(const bf16x8*)((const char*)Bh + byte);
                bl[nt] = *(const bf16x8*)((const char*)Bl + byte);
            }
            #pragma unroll
            for (int mt = 0; mt < 4; ++mt)
                #pragma unroll
                for (int nt = 0; nt < 2; ++nt) {
                    acc[mt][nt] = __builtin_amdgcn_mfma_f32_16x16x32_bf16(ah[mt], bh[nt], acc[mt][nt], 0, 0, 0);
                    acc[mt][nt] = __builtin_amdgcn_mfma_f32_16x16x32_bf16(ah[mt], bl[nt], acc[mt][nt], 0, 0, 0);
                    acc[mt][nt] = __builtin_amdgcn_mfma_f32_16x16x32_bf16(al[mt], bh[nt], acc[mt][nt], 0, 0, 0);
                }
        }
        __syncthreads();   // before next-tile overwrite
    }

    // epilogue: argmin of (c2[n] - 2*dot). C/D: col=lane&15, row=(lane>>4)*4+reg.
    #pragma unroll
    for (int mt = 0; mt < 4; ++mt) {
        #pragma unroll
        for (int reg = 0; reg < 4; ++reg) {
            unsigned long long best = ~0ULL;
            #pragma unroll
            for (int nt = 0; nt < 2; ++nt) {
                int n = n0 + wn * 32 + nt * 16 + li;
                if (n < 1000) {
                    float v = c2[n] - 2.0f * acc[mt][nt][reg];
                    unsigned bi = __float_as_uint(v);
                    bi = (bi & 0x80000000u) ? ~bi : (bi | 0x80000000u);
                    unsigned long long key = ((unsigned long long)bi << 32) | (unsigned)n;
                    if (key < best) best = key;
                }
            }
            #pragma unroll
            for (int d = 1; d < 16; d <<= 1) {
                unsigned long long o = __shfl_xor(best, d, 64);
                if (o < best) best = o;
            }
            if (li == 0) {
                int lr = wm * 64 + mt * 16 + ls * 4 + reg;
                atomicMin(&red[lr], best);
            }
        }
    }
    __syncthreads();
    if (tid < GBM) atomicMin(&packed[m0 + tid], red[tid]);
}

// ---------------------------------------------------------------------------
// Kernel 3: unpack argmin index
// ---------------------------------------------------------------------------
__global__ __launch_bounds__(256) void extract_kernel(
    const unsigned long long* __restrict__ packed, int* __restrict__ out)
{
    int i = blockIdx.x * 256 + threadIdx.x;
    out[i] = (int)(unsigned)(packed[i] & 0xFFFFFFFFull);
}

// ---------------------------------------------------------------------------
extern "C" void kernel_launch(void* const* d_in, const int* in_sizes, int n_in,
                              void* d_out, int out_size, void* d_ws, size_t ws_size,
                              hipStream_t stream)
{
    const float* x    = (const float*)d_in[0];
    const float* w1   = (const float*)d_in[1];
    const float* b1   = (const float*)d_in[2];
    const float* w2   = (const float*)d_in[3];
    const float* b2   = (const float*)d_in[4];
    const float* cent = (const float*)d_in[5];
    int* out = (int*)d_out;

    char* ws = (char*)d_ws;
    u16* f_hi = (u16*)(ws);                          // 4096*4096*2 = 33554432
    u16* f_lo = (u16*)(ws + 33554432);               // 33554432
    u16* c_hi = (u16*)(ws + 67108864);               // 1024*4096*2 = 8388608
    u16* c_lo = (u16*)(ws + 75497472);               // 8388608
    float* c2 = (float*)(ws + 83886080);             // 4096
    unsigned long long* packed =
        (unsigned long long*)(ws + 83890176);        // 32768
    u16* w1t = (u16*)(ws + 83922944);                // 4096
    u16* w2t = (u16*)(ws + 83927040);                // 73728 (dedicated)

    hipMemsetAsync(packed, 0xFF, 4096 * sizeof(unsigned long long), stream);
    prep_w_kernel<<<152, 256, 0, stream>>>(w1, w2, w1t, w2t);
    conv_fused_kernel<<<5096, 256, 0, stream>>>(x, w1t, b1, w2t, b2, f_hi, f_lo,
                                                cent, c_hi, c_lo, c2);
    gemm_argmin_mfma<<<512, 256, 0, stream>>>(f_hi, f_lo, c_hi, c_lo, c2, packed);
    extract_kernel<<<16, 256, 0, stream>>>(packed, out);
}

// Round 16
// 213.612 us; speedup vs baseline: 1.3313x; 1.0399x over previous
//
#include <hip/hip_runtime.h>
#include <hip/hip_bf16.h>
#include <stdint.h>

#define THREADS 256

typedef unsigned short u16;
typedef __attribute__((ext_vector_type(8))) short bf16x8;
typedef __attribute__((ext_vector_type(4))) float f32x4;

// native fp32 -> bf16 (compiler emits v_cvt_pk_bf16_f32 for pairs; HW RNE)
__device__ inline u16 f2bf(float x) {
    __bf16 b = (__bf16)x;
    return __builtin_bit_cast(u16, b);
}
__device__ inline float bf2f(u16 h) { return __uint_as_float(((unsigned)h) << 16); }

// lane^1 exchange via DPP quad_perm(1,0,3,2) -- pure VALU, no LDS pipe
__device__ inline float dpp_xor1(float v) {
    int r = __builtin_amdgcn_mov_dpp(__float_as_int(v), 0xB1, 0xF, 0xF, true);
    return __int_as_float(r);
}

__device__ inline void load_lds16(const void* g, void* l) {
    __builtin_amdgcn_global_load_lds(
        (const __attribute__((address_space(1))) unsigned int*)g,
        (__attribute__((address_space(3))) unsigned int*)l, 16, 0, 0);
}

// ---------------------------------------------------------------------------
// Kernel 0: pre-permute w1 AND w2 into per-lane MFMA A-fragments (split bf16),
// and initialize the packed-argmin buffer (blocks 168-: replaces memset).
// ---------------------------------------------------------------------------
__global__ __launch_bounds__(256) void prep_w_kernel(
    const float* __restrict__ w1, const float* __restrict__ w2,
    u16* __restrict__ w1t, u16* __restrict__ w2t,
    unsigned long long* __restrict__ packed)
{
    if (blockIdx.x < 8) {
        int idx = blockIdx.x * 256 + threadIdx.x;   // 0..2047
        int j     = idx & 7;
        int lane  = (idx >> 3) & 63;
        int mt    = (idx >> 9) & 1;
        int plane = (idx >> 10) & 1;
        int oc = mt * 16 + (lane & 15);
        int k = (lane >> 4) * 8 + j;
        float v = 0.0f;
        if (k < 27) { int ic = k / 9, tap = k - ic * 9; v = w1[oc * 27 + ic * 9 + tap]; }
        u16 hb = f2bf(v);
        w1t[idx] = plane ? f2bf(v - bf2f(hb)) : hb;
    } else if (blockIdx.x < 152) {
        int idx = (blockIdx.x - 8) * 256 + threadIdx.x;   // 0..36863
        int j     = idx & 7;
        int lane  = (idx >> 3) & 63;
        int mt    = (idx >> 9) & 3;
        int plane = (idx >> 11) & 1;
        int tap   = idx >> 12;                      // 0..8
        int oc = mt * 16 + (lane & 15);
        int ic = (lane >> 4) * 8 + j;
        float v = w2[(size_t)oc * 288 + ic * 9 + tap];
        u16 hb = f2bf(v);
        w2t[idx] = plane ? f2bf(v - bf2f(hb)) : hb;
    } else {
        int idx = (blockIdx.x - 152) * 256 + threadIdx.x; // 0..4095
        packed[idx] = ~0ULL;
    }
}

// ---------------------------------------------------------------------------
// Kernel 1: fused conv1(split-bf16 MFMA, tap-packed K=32) +
//           conv2(split-bf16 MFMA, per-tap K=32) + pools -> f
// One image per block (blocks 0..4095), 256 threads (4 waves), 3 blocks/CU.
// Blocks 4096..5095: centroid bf16-split + squared-norm prep.
// Pooling is parity-split: each lane finalizes only its half of the output
// channels; dpp_xor1(oth) delivers the neighbor's value of MY channel
// (oth = the opposite-parity channel on each lane).
// ---------------------------------------------------------------------------
#define XSN (3 * 34 * 34)   // 3468

__global__ __launch_bounds__(256, 3) void conv_fused_kernel(
    const float* __restrict__ x,
    const u16* __restrict__ w1t, const float* __restrict__ b1,
    const u16* __restrict__ w2t, const float* __restrict__ b2,
    u16* __restrict__ f_hi, u16* __restrict__ f_lo,
    const float* __restrict__ cent, u16* __restrict__ c_hi,
    u16* __restrict__ c_lo, float* __restrict__ c2)
{
    const int tid = threadIdx.x;
    const int b = blockIdx.x;

    if (b >= 4096) {
        // ---- centroid prep path (1000 blocks) ----
        __shared__ float wsum[4];
        const int n = b - 4096;
        const size_t base = (size_t)n * 4096;
        float s = 0.0f;
        #pragma unroll
        for (int q = 0; q < 4; ++q) {
            int e = (tid + q * 256) * 4;
            float4 v = *(const float4*)(cent + base + e);
            s = fmaf(v.x, v.x, s); s = fmaf(v.y, v.y, s);
            s = fmaf(v.z, v.z, s); s = fmaf(v.w, v.w, s);
            ushort4 h, l;
            h.x = f2bf(v.x); l.x = f2bf(v.x - bf2f(h.x));
            h.y = f2bf(v.y); l.y = f2bf(v.y - bf2f(h.y));
            h.z = f2bf(v.z); l.z = f2bf(v.z - bf2f(h.z));
            h.w = f2bf(v.w); l.w = f2bf(v.w - bf2f(h.w));
            *(ushort4*)(c_hi + base + e) = h;
            *(ushort4*)(c_lo + base + e) = l;
        }
        #pragma unroll
        for (int off = 32; off >= 1; off >>= 1) s += __shfl_down(s, off, 64);
        int lane = tid & 63, wv = tid >> 6;
        if (lane == 0) wsum[wv] = s;
        __syncthreads();
        if (tid == 0) c2[n] = wsum[0] + wsum[1] + wsum[2] + wsum[3];
        return;
    }

    __shared__ __align__(16) unsigned xsi[XSN];         // padded image {hi,lo} (13.9 KB)
    __shared__ __align__(16) u16 h1hi[16 * 16 * 32];    // [y][x][ic] bf16 hi (16.4 KB)
    __shared__ __align__(16) u16 h1lo[16 * 16 * 32];    // [y][x][ic] bf16 lo (16.4 KB)

    const int lane = tid & 63;
    const int li = lane & 15, ls = lane >> 4;
    const int wv = tid >> 6;
    const int myMt = li & 1;     // parity: which half of channels this lane finalizes
    __builtin_assume(li >= 0 && li < 16);
    __builtin_assume(ls >= 0 && ls < 4);
    __builtin_assume(wv >= 0 && wv < 4);

    // phase A: zero xsi (halo must be 0)
    for (int i = tid; i < XSN; i += THREADS) xsi[i] = 0u;
    __syncthreads();

    // phase B: load image interior, split to bf16 hi/lo ONCE (interleaved)
    const float* xb = x + (size_t)b * 3072;
    #pragma unroll
    for (int q = 0; q < 3; ++q) {
        int idx = tid + q * THREADS;      // 0..767
        int ic  = idx >> 8;
        int rem = idx & 255;
        int y   = rem >> 3;
        int x4  = (rem & 7) << 2;
        float4 v = *(const float4*)(xb + ic * 1024 + y * 32 + x4);
        int base = ic * 1156 + (1 + y) * 34 + 1 + x4;
        float vv[4] = {v.x, v.y, v.z, v.w};
        #pragma unroll
        for (int e = 0; e < 4; ++e) {
            u16 hb = f2bf(vv[e]);
            u16 lb = f2bf(vv[e] - bf2f(hb));
            xsi[base + e] = (unsigned)hb | ((unsigned)lb << 16);
        }
    }
    __syncthreads();

    // phase C: conv1 via MFMA (tap-packed K=32, 3-term split) + pool -> h1
    {
        bf16x8 aH1[2], aL1[2];
        #pragma unroll
        for (int mt = 0; mt < 2; ++mt) {
            aH1[mt] = *(const bf16x8*)(w1t + (size_t)((0 * 2 + mt) * 64 + lane) * 8);
            aL1[mt] = *(const bf16x8*)(w1t + (size_t)((1 * 2 + mt) * 64 + lane) * 8);
        }
        int koffc[8];
        #pragma unroll
        for (int j = 0; j < 8; ++j) {
            int k = ls * 8 + j;
            int kc = (k < 27) ? k : 0;
            int ic = kc / 9, tap = kc - ic * 9;
            int ky = tap / 3, kx = tap - ky * 3;
            koffc[j] = ic * 1156 + ky * 34 + kx;
        }
        float b1v[2][4];
        #pragma unroll
        for (int mt = 0; mt < 2; ++mt)
            #pragma unroll
            for (int reg = 0; reg < 4; ++reg)
                b1v[mt][reg] = b1[16 * mt + 4 * ls + reg];

        #pragma unroll
        for (int q = 0; q < 4; ++q) {           // row-pair quad
            f32x4 acc[4][2];
            #pragma unroll
            for (int s = 0; s < 4; ++s)
                #pragma unroll
                for (int mt = 0; mt < 2; ++mt)
                    acc[s][mt] = (f32x4){b1v[mt][0], b1v[mt][1], b1v[mt][2], b1v[mt][3]};

            #pragma unroll
            for (int s = 0; s < 4; ++s) {       // s: (row-lsb, col-half)
                int y = 8 * wv + 2 * q + (s >> 1);
                int xcol = 16 * (s & 1) + li;
                int base = y * 34 + xcol;
                int4 vH, vL;
                #pragma unroll
                for (int jj = 0; jj < 4; ++jj) {
                    unsigned d0 = xsi[base + koffc[2 * jj + 0]];
                    unsigned d1 = xsi[base + koffc[2 * jj + 1]];
                    ((int*)&vH)[jj] = __builtin_amdgcn_perm(d1, d0, 0x05040100u);
                    ((int*)&vL)[jj] = __builtin_amdgcn_perm(d1, d0, 0x07060302u);
                }
                bf16x8 bH = __builtin_bit_cast(bf16x8, vH);
                bf16x8 bL = __builtin_bit_cast(bf16x8, vL);
                #pragma unroll
                for (int mt = 0; mt < 2; ++mt) {
                    acc[s][mt] = __builtin_amdgcn_mfma_f32_16x16x32_bf16(aH1[mt], bH, acc[s][mt], 0, 0, 0);
                    acc[s][mt] = __builtin_amdgcn_mfma_f32_16x16x32_bf16(aH1[mt], bL, acc[s][mt], 0, 0, 0);
                    acc[s][mt] = __builtin_amdgcn_mfma_f32_16x16x32_bf16(aL1[mt], bH, acc[s][mt], 0, 0, 0);
                }
            }
            // pool quad (parity-split): each lane finalizes mt = myMt only.
            // oth = opposite-parity channel so dpp_xor1 delivers neighbor's myMt value.
            int py = 4 * wv + q;
            #pragma unroll
            for (int h = 0; h < 2; ++h) {
                f32x4 s0 = myMt ? acc[h][1]     : acc[h][0];
                f32x4 o0 = myMt ? acc[h][0]     : acc[h][1];
                f32x4 s1 = myMt ? acc[h + 2][1] : acc[h + 2][0];
                f32x4 o1 = myMt ? acc[h + 2][0] : acc[h + 2][1];
                ushort4 pH, pL;
                #pragma unroll
                for (int reg = 0; reg < 4; ++reg) {
                    float m0 = fmaxf(s0[reg], dpp_xor1(o0[reg]));
                    float m1 = fmaxf(s1[reg], dpp_xor1(o1[reg]));
                    float v = fmaxf(fmaxf(m0, m1), 0.0f);   // bias already in acc
                    u16 hb = f2bf(v);
                    ((u16*)&pH)[reg] = hb;
                    ((u16*)&pL)[reg] = f2bf(v - bf2f(hb));
                }
                int px = (li >> 1) + 8 * h;
                int ib = 2 * myMt + (ls >> 1);   // logical slot (oc>>3)
                int byte = (py * 16 + px) * 64 + ((ib ^ ((px >> 1) & 3)) << 4) + (ls & 1) * 8;
                *(ushort4*)((char*)h1hi + byte) = pH;
                *(ushort4*)((char*)h1lo + byte) = pL;
            }
        }
    }
    __syncthreads();

    // phase D: conv2 via split-bf16 MFMA (3-term), kx-outer with row caching
    {
        const bf16x8 zf = {0, 0, 0, 0, 0, 0, 0, 0};

        float b2v[4][4];
        #pragma unroll
        for (int mt = 0; mt < 4; ++mt)
            #pragma unroll
            for (int reg = 0; reg < 4; ++reg)
                b2v[mt][reg] = b2[mt * 16 + ls * 4 + reg];

        f32x4 acc[4][4];                    // [mt][ntl], bias-initialized
        #pragma unroll
        for (int mt = 0; mt < 4; ++mt)
            #pragma unroll
            for (int ntl = 0; ntl < 4; ++ntl)
                acc[mt][ntl] = (f32x4){b2v[mt][0], b2v[mt][1], b2v[mt][2], b2v[mt][3]};

        #pragma unroll
        for (int kx = 0; kx < 3; ++kx) {
            int xg = li + kx - 1;                 // -1..16
            bool xo = (unsigned)xg > 15u;
            int xc = min(max(xg, 0), 15);
            int slotb = (ls ^ ((xc >> 1) & 3)) << 4;

            // cache interior rows d = 0..4 (yg = 4wv+d), used up to 3x each
            bf16x8 cH[5], cL[5];
            #pragma unroll
            for (int d = 0; d < 5; ++d) {
                int yg = 4 * wv + d;
                if (yg <= 15) {
                    int byte = (yg * 16 + xc) * 64 + slotb;
                    bf16x8 h = *(const bf16x8*)((const char*)h1hi + byte);
                    bf16x8 l = *(const bf16x8*)((const char*)h1lo + byte);
                    cH[d] = xo ? zf : h;
                    cL[d] = xo ? zf : l;
                } else { cH[d] = zf; cL[d] = zf; }
            }

            #pragma unroll
            for (int ky = 0; ky < 3; ++ky) {
                const int tap = ky * 3 + kx;
                bf16x8 aH[4], aL[4];
                #pragma unroll
                for (int mt = 0; mt < 4; ++mt) {
                    aH[mt] = *(const bf16x8*)(w2t + (size_t)(tap * 4096 + mt * 512 + lane * 8));
                    aL[mt] = *(const bf16x8*)(w2t + (size_t)(tap * 4096 + 2048 + mt * 512 + lane * 8));
                }
                #pragma unroll
                for (int ntl = 0; ntl < 4; ++ntl) {
                    int d = ntl + ky - 1;         // -1..5
                    int yg = 4 * wv + d;
                    if ((unsigned)yg > 15u) continue;   // zero-row tap (uniform)
                    bf16x8 bH, bL;
                    if (d == -1 || d == 5) {      // edge rows: on-demand read
                        int byte = (yg * 16 + xc) * 64 + slotb;
                        bH = *(const bf16x8*)((const char*)h1hi + byte);
                        bL = *(const bf16x8*)((const char*)h1lo + byte);
                        if (xo) { bH = zf; bL = zf; }
                    } else {
                        bH = cH[d]; bL = cL[d];
                    }
                    #pragma unroll
                    for (int mt = 0; mt < 4; ++mt) {
                        acc[mt][ntl] = __builtin_amdgcn_mfma_f32_16x16x32_bf16(aH[mt], bH, acc[mt][ntl], 0, 0, 0);
                        acc[mt][ntl] = __builtin_amdgcn_mfma_f32_16x16x32_bf16(aH[mt], bL, acc[mt][ntl], 0, 0, 0);
                        acc[mt][ntl] = __builtin_amdgcn_mfma_f32_16x16x32_bf16(aL[mt], bH, acc[mt][ntl], 0, 0, 0);
                    }
                }
            }
        }

        // epilogue (parity-split): lane finalizes mt = 2*myMt + t, t in {0,1}.
        const size_t fbase = (size_t)b * 4096;
        #pragma unroll
        for (int t = 0; t < 2; ++t) {
            int mt = 2 * myMt + t;     // runtime scalar (never an array index)
            #pragma unroll
            for (int p = 0; p < 2; ++p) {
                f32x4 sa = myMt ? acc[t + 2][2 * p + 0] : acc[t][2 * p + 0];
                f32x4 oa = myMt ? acc[t][2 * p + 0]     : acc[t + 2][2 * p + 0];
                f32x4 sb = myMt ? acc[t + 2][2 * p + 1] : acc[t][2 * p + 1];
                f32x4 ob = myMt ? acc[t][2 * p + 1]     : acc[t + 2][2 * p + 1];
                #pragma unroll
                for (int reg = 0; reg < 4; ++reg) {
                    float x0 = fmaxf(sa[reg], dpp_xor1(oa[reg]));
                    float x1 = fmaxf(sb[reg], dpp_xor1(ob[reg]));
                    float v = fmaxf(fmaxf(x0, x1), 0.0f);   // bias already in acc
                    int oc = mt * 16 + ls * 4 + reg;
                    int py = 2 * wv + p, px = li >> 1;
                    u16 hb = f2bf(v);
                    u16 lb = f2bf(v - bf2f(hb));
                    size_t o = fbase + (size_t)oc * 64 + py * 8 + px;
                    f_hi[o] = hb;
                    f_lo[o] = lb;
                }
            }
        }
    }
}

// ---------------------------------------------------------------------------
// Kernel 2: split-bf16 MFMA GEMM (f . cent^T, 3-term, 128x64 tile, BK=64,
// grid 512) + fused argmin epilogue. Single-buffer 2-barrier structure.
// XCD-disjoint f mapping: xcd=id&7; g=id>>3; mb=xcd*4+(g&3); nb=g>>2.
// Swizzle: 8 slots/row, slot ^= row&7 (involution; 2-way read = free).
// ---------------------------------------------------------------------------
#define GBM 128
#define GBN 64
#define GBK 64

__global__ __launch_bounds__(256, 3) void gemm_argmin_mfma(
    const u16* __restrict__ f_hi, const u16* __restrict__ f_lo,
    const u16* __restrict__ c_hi, const u16* __restrict__ c_lo,
    const float* __restrict__ c2, unsigned long long* __restrict__ packed)
{
    __shared__ __align__(16) u16 Ah[GBM * GBK];   // 16 KB
    __shared__ __align__(16) u16 Al[GBM * GBK];   // 16 KB
    __shared__ __align__(16) u16 Bh[GBN * GBK];   // 8 KB
    __shared__ __align__(16) u16 Bl[GBN * GBK];   // 8 KB
    __shared__ unsigned long long red[GBM];

    const int tid = threadIdx.x;
    const int id = blockIdx.x;
    const int xcd = id & 7;
    const int g = id >> 3;
    const int mb = xcd * 4 + (g & 3);   // 4 disjoint m-panels per XCD
    const int nb = g >> 2;              // all 16 n-panels per XCD
    const int m0 = mb * GBM;
    const int n0 = nb * GBN;

    const int lane = tid & 63;
    const int wid  = tid >> 6;
    const int wm = wid >> 1, wn = wid & 1;
    const int li = lane & 15;
    const int ls = lane >> 4;

    if (tid < GBM) red[tid] = ~0ULL;

    f32x4 acc[4][2];
    #pragma unroll
    for (int i = 0; i < 4; ++i)
        #pragma unroll
        for (int j = 0; j < 2; ++j) acc[i][j] = (f32x4){0.f, 0.f, 0.f, 0.f};

    for (int k0 = 0; k0 < 4096; k0 += GBK) {
        // stage A: 128 rows x 64 k (1024 16B-chunks per plane), swizzled source
        #pragma unroll
        for (int q = 0; q < 4; ++q) {
            int idx = tid + q * 256;          // 0..1023
            int row = idx >> 3, slot = idx & 7;
            int kg = k0 + ((slot ^ (row & 7)) << 3);
            size_t goff = (size_t)(m0 + row) * 4096 + kg;
            load_lds16(f_hi + goff, &Ah[idx * 8]);
            load_lds16(f_lo + goff, &Al[idx * 8]);
        }
        // stage B: 64 rows x 64 k (512 chunks per plane)
        #pragma unroll
        for (int q = 0; q < 2; ++q) {
            int idx = tid + q * 256;          // 0..511
            int row = idx >> 3, slot = idx & 7;
            int kg = k0 + ((slot ^ (row & 7)) << 3);
            size_t goff = (size_t)(n0 + row) * 4096 + kg;
            load_lds16(c_hi + goff, &Bh[idx * 8]);
            load_lds16(c_lo + goff, &Bl[idx * 8]);
        }
        __syncthreads();   // drains vmcnt -> tile resident

        #pragma unroll
        for (int ks = 0; ks < 2; ++ks) {      // two K=32 sub-steps
            const int c = ks * 4 + ls;        // global 16B k-chunk index
            bf16x8 ah[4], al[4], bh[2], bl[2];
            #pragma unroll
            for (int mt = 0; mt < 4; ++mt) {
                int r = wm * 64 + mt * 16 + li;
                int byte = r * 128 + ((c ^ (r & 7)) << 4);
                ah[mt] = *(const bf16x8*)((const char*)Ah + byte);
                al[mt] = *(const bf16x8*)((const char*)Al + byte);
            }
            #pragma unroll
            for (int nt = 0; nt < 2; ++nt) {
                int r = wn * 32 + nt * 16 + li;
                int byte = r * 128 + ((c ^ (r & 7)) << 4);
                bh[nt] = *(const bf16x8*)((const char*)Bh + byte);
                bl[nt] = *(const bf16x8*)((const char*)Bl + byte);
            }
            #pragma unroll
            for (int mt = 0; mt < 4; ++mt)
                #pragma unroll
                for (int nt = 0; nt < 2; ++nt) {
                    acc[mt][nt] = __builtin_amdgcn_mfma_f32_16x16x32_bf16(ah[mt], bh[nt], acc[mt][nt], 0, 0, 0);
                    acc[mt][nt] = __builtin_amdgcn_mfma_f32_16x16x32_bf16(ah[mt], bl[nt], acc[mt][nt], 0, 0, 0);
                    acc[mt][nt] = __builtin_amdgcn_mfma_f32_16x16x32_bf16(al[mt], bh[nt], acc[mt][nt], 0, 0, 0);
                }
        }
        __syncthreads();   // before next-tile overwrite
    }

    // epilogue: argmin of (c2[n] - 2*dot). C/D: col=lane&15, row=(lane>>4)*4+reg.
    #pragma unroll
    for (int mt = 0; mt < 4; ++mt) {
        #pragma unroll
        for (int reg = 0; reg < 4; ++reg) {
            unsigned long long best = ~0ULL;
            #pragma unroll
            for (int nt = 0; nt < 2; ++nt) {
                int n = n0 + wn * 32 + nt * 16 + li;
                if (n < 1000) {
                    float v = c2[n] - 2.0f * acc[mt][nt][reg];
                    unsigned bi = __float_as_uint(v);
                    bi = (bi & 0x80000000u) ? ~bi : (bi | 0x80000000u);
                    unsigned long long key = ((unsigned long long)bi << 32) | (unsigned)n;
                    if (key < best) best = key;
                }
            }
            #pragma unroll
            for (int d = 1; d < 16; d <<= 1) {
                unsigned long long o = __shfl_xor(best, d, 64);
                if (o < best) best = o;
            }
            if (li == 0) {
                int lr = wm * 64 + mt * 16 + ls * 4 + reg;
                atomicMin(&red[lr], best);
            }
        }
    }
    __syncthreads();
    if (tid < GBM) atomicMin(&packed[m0 + tid], red[tid]);
}

// ---------------------------------------------------------------------------
// Kernel 3: unpack argmin index
// ---------------------------------------------------------------------------
__global__ __launch_bounds__(256) void extract_kernel(
    const unsigned long long* __restrict__ packed, int* __restrict__ out)
{
    int i = blockIdx.x * 256 + threadIdx.x;
    out[i] = (int)(unsigned)(packed[i] & 0xFFFFFFFFull);
}

// ---------------------------------------------------------------------------
extern "C" void kernel_launch(void* const* d_in, const int* in_sizes, int n_in,
                              void* d_out, int out_size, void* d_ws, size_t ws_size,
                              hipStream_t stream)
{
    const float* x    = (const float*)d_in[0];
    const float* w1   = (const float*)d_in[1];
    const float* b1   = (const float*)d_in[2];
    const float* w2   = (const float*)d_in[3];
    const float* b2   = (const float*)d_in[4];
    const float* cent = (const float*)d_in[5];
    int* out = (int*)d_out;

    char* ws = (char*)d_ws;
    u16* f_hi = (u16*)(ws);                          // 4096*4096*2 = 33554432
    u16* f_lo = (u16*)(ws + 33554432);               // 33554432
    u16* c_hi = (u16*)(ws + 67108864);               // 1024*4096*2 = 8388608
    u16* c_lo = (u16*)(ws + 75497472);               // 8388608
    float* c2 = (float*)(ws + 83886080);             // 4096
    unsigned long long* packed =
        (unsigned long long*)(ws + 83890176);        // 32768
    u16* w1t = (u16*)(ws + 83922944);                // 4096
    u16* w2t = (u16*)(ws + 83927040);                // 73728 (dedicated)

    prep_w_kernel<<<168, 256, 0, stream>>>(w1, w2, w1t, w2t, packed);
    conv_fused_kernel<<<5096, 256, 0, stream>>>(x, w1t, b1, w2t, b2, f_hi, f_lo,
                                                cent, c_hi, c_lo, c2);
    gemm_argmin_mfma<<<512, 256, 0, stream>>>(f_hi, f_lo, c_hi, c_lo, c2, packed);
    extract_kernel<<<16, 256, 0, stream>>>(packed, out);
}

// Round 17
// 206.283 us; speedup vs baseline: 1.3786x; 1.0355x over previous
//
#include <hip/hip_runtime.h>
#include <hip/hip_bf16.h>
#include <stdint.h>

#define THREADS 256

typedef unsigned short u16;
typedef __attribute__((ext_vector_type(8))) short bf16x8;
typedef __attribute__((ext_vector_type(4))) float f32x4;

// native fp32 -> bf16 (compiler emits v_cvt_pk_bf16_f32 for pairs; HW RNE)
__device__ inline u16 f2bf(float x) {
    __bf16 b = (__bf16)x;
    return __builtin_bit_cast(u16, b);
}
__device__ inline float bf2f(u16 h) { return __uint_as_float(((unsigned)h) << 16); }

// lane^1 exchange via DPP quad_perm(1,0,3,2) -- pure VALU, no LDS pipe
__device__ inline float dpp_xor1(float v) {
    int r = __builtin_amdgcn_mov_dpp(__float_as_int(v), 0xB1, 0xF, 0xF, true);
    return __int_as_float(r);
}

__device__ inline void load_lds16(const void* g, void* l) {
    __builtin_amdgcn_global_load_lds(
        (const __attribute__((address_space(1))) unsigned int*)g,
        (__attribute__((address_space(3))) unsigned int*)l, 16, 0, 0);
}

// ---------------------------------------------------------------------------
// Kernel 0: pre-permute w1 AND w2 into per-lane MFMA A-fragments (split bf16),
// and initialize the packed-argmin buffer (blocks 152+: replaces memset).
// ---------------------------------------------------------------------------
__global__ __launch_bounds__(256) void prep_w_kernel(
    const float* __restrict__ w1, const float* __restrict__ w2,
    u16* __restrict__ w1t, u16* __restrict__ w2t,
    unsigned long long* __restrict__ packed)
{
    if (blockIdx.x < 8) {
        int idx = blockIdx.x * 256 + threadIdx.x;   // 0..2047
        int j     = idx & 7;
        int lane  = (idx >> 3) & 63;
        int mt    = (idx >> 9) & 1;
        int plane = (idx >> 10) & 1;
        int oc = mt * 16 + (lane & 15);
        int k = (lane >> 4) * 8 + j;
        float v = 0.0f;
        if (k < 27) { int ic = k / 9, tap = k - ic * 9; v = w1[oc * 27 + ic * 9 + tap]; }
        u16 hb = f2bf(v);
        w1t[idx] = plane ? f2bf(v - bf2f(hb)) : hb;
    } else if (blockIdx.x < 152) {
        int idx = (blockIdx.x - 8) * 256 + threadIdx.x;   // 0..36863
        int j     = idx & 7;
        int lane  = (idx >> 3) & 63;
        int mt    = (idx >> 9) & 3;
        int plane = (idx >> 11) & 1;
        int tap   = idx >> 12;                      // 0..8
        int oc = mt * 16 + (lane & 15);
        int ic = (lane >> 4) * 8 + j;
        float v = w2[(size_t)oc * 288 + ic * 9 + tap];
        u16 hb = f2bf(v);
        w2t[idx] = plane ? f2bf(v - bf2f(hb)) : hb;
    } else {
        int idx = (blockIdx.x - 152) * 256 + threadIdx.x; // 0..4095
        packed[idx] = ~0ULL;
    }
}

// ---------------------------------------------------------------------------
// Kernel 1: fused conv1(split-bf16 MFMA, tap-packed K=32) +
//           conv2(split-bf16 MFMA, per-tap K=32) + pools -> f
// One image per block (blocks 0..4095), 256 threads (4 waves), 3 blocks/CU.
// Blocks 4096..5095: centroid bf16-split + squared-norm prep.
// T5: s_setprio(1) around MFMA clusters (conv blocks are independently
// phased -> scheduler favors the MFMA-entering wave; m191 mechanism).
// Phase A zeroes ONLY the 396 halo cells (interior overwritten by phase B).
// ---------------------------------------------------------------------------
#define XSN (3 * 34 * 34)   // 3468

__global__ __launch_bounds__(256, 3) void conv_fused_kernel(
    const float* __restrict__ x,
    const u16* __restrict__ w1t, const float* __restrict__ b1,
    const u16* __restrict__ w2t, const float* __restrict__ b2,
    u16* __restrict__ f_hi, u16* __restrict__ f_lo,
    const float* __restrict__ cent, u16* __restrict__ c_hi,
    u16* __restrict__ c_lo, float* __restrict__ c2)
{
    const int tid = threadIdx.x;
    const int b = blockIdx.x;

    if (b >= 4096) {
        // ---- centroid prep path (1000 blocks) ----
        __shared__ float wsum[4];
        const int n = b - 4096;
        const size_t base = (size_t)n * 4096;
        float s = 0.0f;
        #pragma unroll
        for (int q = 0; q < 4; ++q) {
            int e = (tid + q * 256) * 4;
            float4 v = *(const float4*)(cent + base + e);
            s = fmaf(v.x, v.x, s); s = fmaf(v.y, v.y, s);
            s = fmaf(v.z, v.z, s); s = fmaf(v.w, v.w, s);
            ushort4 h, l;
            h.x = f2bf(v.x); l.x = f2bf(v.x - bf2f(h.x));
            h.y = f2bf(v.y); l.y = f2bf(v.y - bf2f(h.y));
            h.z = f2bf(v.z); l.z = f2bf(v.z - bf2f(h.z));
            h.w = f2bf(v.w); l.w = f2bf(v.w - bf2f(h.w));
            *(ushort4*)(c_hi + base + e) = h;
            *(ushort4*)(c_lo + base + e) = l;
        }
        #pragma unroll
        for (int off = 32; off >= 1; off >>= 1) s += __shfl_down(s, off, 64);
        int lane = tid & 63, wv = tid >> 6;
        if (lane == 0) wsum[wv] = s;
        __syncthreads();
        if (tid == 0) c2[n] = wsum[0] + wsum[1] + wsum[2] + wsum[3];
        return;
    }

    __shared__ __align__(16) unsigned xsi[XSN];         // padded image {hi,lo} (13.9 KB)
    __shared__ __align__(16) u16 h1hi[16 * 16 * 32];    // [y][x][ic] bf16 hi (16.4 KB)
    __shared__ __align__(16) u16 h1lo[16 * 16 * 32];    // [y][x][ic] bf16 lo (16.4 KB)

    const int lane = tid & 63;
    const int li = lane & 15, ls = lane >> 4;
    const int wv = tid >> 6;
    const int myMt = li & 1;     // parity: which half of channels this lane finalizes
    __builtin_assume(li >= 0 && li < 16);
    __builtin_assume(ls >= 0 && ls < 4);
    __builtin_assume(wv >= 0 && wv < 4);

    // phase A: zero ONLY the halo (396 cells); interior is written by phase B
    #pragma unroll
    for (int q = 0; q < 2; ++q) {
        int t = tid + q * 256;
        if (t < 396) {
            int ic = t / 132, c = t - ic * 132;
            int off;
            if (c < 34)       off = c;                      // row 0
            else if (c < 68)  off = 33 * 34 + (c - 34);     // row 33
            else if (c < 100) off = (c - 68 + 1) * 34;      // col 0, rows 1..32
            else              off = (c - 100 + 1) * 34 + 33;// col 33, rows 1..32
            xsi[ic * 1156 + off] = 0u;
        }
    }
    __syncthreads();

    // phase B: load image interior, split to bf16 hi/lo ONCE (interleaved)
    const float* xb = x + (size_t)b * 3072;
    #pragma unroll
    for (int q = 0; q < 3; ++q) {
        int idx = tid + q * THREADS;      // 0..767
        int ic  = idx >> 8;
        int rem = idx & 255;
        int y   = rem >> 3;
        int x4  = (rem & 7) << 2;
        float4 v = *(const float4*)(xb + ic * 1024 + y * 32 + x4);
        int base = ic * 1156 + (1 + y) * 34 + 1 + x4;
        float vv[4] = {v.x, v.y, v.z, v.w};
        #pragma unroll
        for (int e = 0; e < 4; ++e) {
            u16 hb = f2bf(vv[e]);
            u16 lb = f2bf(vv[e] - bf2f(hb));
            xsi[base + e] = (unsigned)hb | ((unsigned)lb << 16);
        }
    }
    __syncthreads();

    // phase C: conv1 via MFMA (tap-packed K=32, 3-term split) + pool -> h1
    {
        bf16x8 aH1[2], aL1[2];
        #pragma unroll
        for (int mt = 0; mt < 2; ++mt) {
            aH1[mt] = *(const bf16x8*)(w1t + (size_t)((0 * 2 + mt) * 64 + lane) * 8);
            aL1[mt] = *(const bf16x8*)(w1t + (size_t)((1 * 2 + mt) * 64 + lane) * 8);
        }
        int koffc[8];
        #pragma unroll
        for (int j = 0; j < 8; ++j) {
            int k = ls * 8 + j;
            int kc = (k < 27) ? k : 0;
            int ic = kc / 9, tap = kc - ic * 9;
            int ky = tap / 3, kx = tap - ky * 3;
            koffc[j] = ic * 1156 + ky * 34 + kx;
        }
        float b1v[2][4];
        #pragma unroll
        for (int mt = 0; mt < 2; ++mt)
            #pragma unroll
            for (int reg = 0; reg < 4; ++reg)
                b1v[mt][reg] = b1[16 * mt + 4 * ls + reg];

        #pragma unroll
        for (int q = 0; q < 4; ++q) {           // row-pair quad
            f32x4 acc[4][2];
            #pragma unroll
            for (int s = 0; s < 4; ++s)
                #pragma unroll
                for (int mt = 0; mt < 2; ++mt)
                    acc[s][mt] = (f32x4){b1v[mt][0], b1v[mt][1], b1v[mt][2], b1v[mt][3]};

            #pragma unroll
            for (int s = 0; s < 4; ++s) {       // s: (row-lsb, col-half)
                int y = 8 * wv + 2 * q + (s >> 1);
                int xcol = 16 * (s & 1) + li;
                int base = y * 34 + xcol;
                int4 vH, vL;
                #pragma unroll
                for (int jj = 0; jj < 4; ++jj) {
                    unsigned d0 = xsi[base + koffc[2 * jj + 0]];
                    unsigned d1 = xsi[base + koffc[2 * jj + 1]];
                    ((int*)&vH)[jj] = __builtin_amdgcn_perm(d1, d0, 0x05040100u);
                    ((int*)&vL)[jj] = __builtin_amdgcn_perm(d1, d0, 0x07060302u);
                }
                bf16x8 bH = __builtin_bit_cast(bf16x8, vH);
                bf16x8 bL = __builtin_bit_cast(bf16x8, vL);
                __builtin_amdgcn_s_setprio(1);
                #pragma unroll
                for (int mt = 0; mt < 2; ++mt) {
                    acc[s][mt] = __builtin_amdgcn_mfma_f32_16x16x32_bf16(aH1[mt], bH, acc[s][mt], 0, 0, 0);
                    acc[s][mt] = __builtin_amdgcn_mfma_f32_16x16x32_bf16(aH1[mt], bL, acc[s][mt], 0, 0, 0);
                    acc[s][mt] = __builtin_amdgcn_mfma_f32_16x16x32_bf16(aL1[mt], bH, acc[s][mt], 0, 0, 0);
                }
                __builtin_amdgcn_s_setprio(0);
            }
            // pool quad (parity-split): each lane finalizes mt = myMt only.
            int py = 4 * wv + q;
            #pragma unroll
            for (int h = 0; h < 2; ++h) {
                f32x4 s0 = myMt ? acc[h][1]     : acc[h][0];
                f32x4 o0 = myMt ? acc[h][0]     : acc[h][1];
                f32x4 s1 = myMt ? acc[h + 2][1] : acc[h + 2][0];
                f32x4 o1 = myMt ? acc[h + 2][0] : acc[h + 2][1];
                ushort4 pH, pL;
                #pragma unroll
                for (int reg = 0; reg < 4; ++reg) {
                    float m0 = fmaxf(s0[reg], dpp_xor1(o0[reg]));
                    float m1 = fmaxf(s1[reg], dpp_xor1(o1[reg]));
                    float v = fmaxf(fmaxf(m0, m1), 0.0f);   // bias already in acc
                    u16 hb = f2bf(v);
                    ((u16*)&pH)[reg] = hb;
                    ((u16*)&pL)[reg] = f2bf(v - bf2f(hb));
                }
                int px = (li >> 1) + 8 * h;
                int ib = 2 * myMt + (ls >> 1);   // logical slot (oc>>3)
                int byte = (py * 16 + px) * 64 + ((ib ^ ((px >> 1) & 3)) << 4) + (ls & 1) * 8;
                *(ushort4*)((char*)h1hi + byte) = pH;
                *(ushort4*)((char*)h1lo + byte) = pL;
            }
        }
    }
    __syncthreads();

    // phase D: conv2 via split-bf16 MFMA (3-term), kx-outer with row caching
    {
        const bf16x8 zf = {0, 0, 0, 0, 0, 0, 0, 0};

        float b2v[4][4];
        #pragma unroll
        for (int mt = 0; mt < 4; ++mt)
            #pragma unroll
            for (int reg = 0; reg < 4; ++reg)
                b2v[mt][reg] = b2[mt * 16 + ls * 4 + reg];

        f32x4 acc[4][4];                    // [mt][ntl], bias-initialized
        #pragma unroll
        for (int mt = 0; mt < 4; ++mt)
            #pragma unroll
            for (int ntl = 0; ntl < 4; ++ntl)
                acc[mt][ntl] = (f32x4){b2v[mt][0], b2v[mt][1], b2v[mt][2], b2v[mt][3]};

        #pragma unroll
        for (int kx = 0; kx < 3; ++kx) {
            int xg = li + kx - 1;                 // -1..16
            bool xo = (unsigned)xg > 15u;
            int xc = min(max(xg, 0), 15);
            int slotb = (ls ^ ((xc >> 1) & 3)) << 4;

            // cache interior rows d = 0..4 (yg = 4wv+d), used up to 3x each
            bf16x8 cH[5], cL[5];
            #pragma unroll
            for (int d = 0; d < 5; ++d) {
                int yg = 4 * wv + d;
                if (yg <= 15) {
                    int byte = (yg * 16 + xc) * 64 + slotb;
                    bf16x8 h = *(const bf16x8*)((const char*)h1hi + byte);
                    bf16x8 l = *(const bf16x8*)((const char*)h1lo + byte);
                    cH[d] = xo ? zf : h;
                    cL[d] = xo ? zf : l;
                } else { cH[d] = zf; cL[d] = zf; }
            }

            #pragma unroll
            for (int ky = 0; ky < 3; ++ky) {
                const int tap = ky * 3 + kx;
                bf16x8 aH[4], aL[4];
                #pragma unroll
                for (int mt = 0; mt < 4; ++mt) {
                    aH[mt] = *(const bf16x8*)(w2t + (size_t)(tap * 4096 + mt * 512 + lane * 8));
                    aL[mt] = *(const bf16x8*)(w2t + (size_t)(tap * 4096 + 2048 + mt * 512 + lane * 8));
                }
                #pragma unroll
                for (int ntl = 0; ntl < 4; ++ntl) {
                    int d = ntl + ky - 1;         // -1..5
                    int yg = 4 * wv + d;
                    if ((unsigned)yg > 15u) continue;   // zero-row tap (uniform)
                    bf16x8 bH, bL;
                    if (d == -1 || d == 5) {      // edge rows: on-demand read
                        int byte = (yg * 16 + xc) * 64 + slotb;
                        bH = *(const bf16x8*)((const char*)h1hi + byte);
                        bL = *(const bf16x8*)((const char*)h1lo + byte);
                        if (xo) { bH = zf; bL = zf; }
                    } else {
                        bH = cH[d]; bL = cL[d];
                    }
                    __builtin_amdgcn_s_setprio(1);
                    #pragma unroll
                    for (int mt = 0; mt < 4; ++mt) {
                        acc[mt][ntl] = __builtin_amdgcn_mfma_f32_16x16x32_bf16(aH[mt], bH, acc[mt][ntl], 0, 0, 0);
                        acc[mt][ntl] = __builtin_amdgcn_mfma_f32_16x16x32_bf16(aH[mt], bL, acc[mt][ntl], 0, 0, 0);
                        acc[mt][ntl] = __builtin_amdgcn_mfma_f32_16x16x32_bf16(aL[mt], bH, acc[mt][ntl], 0, 0, 0);
                    }
                    __builtin_amdgcn_s_setprio(0);
                }
            }
        }

        // epilogue (parity-split): lane finalizes mt = 2*myMt + t, t in {0,1}.
        const size_t fbase = (size_t)b * 4096;
        #pragma unroll
        for (int t = 0; t < 2; ++t) {
            int mt = 2 * myMt + t;     // runtime scalar (never an array index)
            #pragma unroll
            for (int p = 0; p < 2; ++p) {
                f32x4 sa = myMt ? acc[t + 2][2 * p + 0] : acc[t][2 * p + 0];
                f32x4 oa = myMt ? acc[t][2 * p + 0]     : acc[t + 2][2 * p + 0];
                f32x4 sb = myMt ? acc[t + 2][2 * p + 1] : acc[t][2 * p + 1];
                f32x4 ob = myMt ? acc[t][2 * p + 1]     : acc[t + 2][2 * p + 1];
                #pragma unroll
                for (int reg = 0; reg < 4; ++reg) {
                    float x0 = fmaxf(sa[reg], dpp_xor1(oa[reg]));
                    float x1 = fmaxf(sb[reg], dpp_xor1(ob[reg]));
                    float v = fmaxf(fmaxf(x0, x1), 0.0f);   // bias already in acc
                    int oc = mt * 16 + ls * 4 + reg;
                    int py = 2 * wv + p, px = li >> 1;
                    u16 hb = f2bf(v);
                    u16 lb = f2bf(v - bf2f(hb));
                    size_t o = fbase + (size_t)oc * 64 + py * 8 + px;
                    f_hi[o] = hb;
                    f_lo[o] = lb;
                }
            }
        }
    }
}

// ---------------------------------------------------------------------------
// Kernel 2: split-bf16 MFMA GEMM (f . cent^T, 3-term, 128x64 tile, BK=64,
// grid 512) + fused argmin epilogue. Single-buffer 2-barrier structure.
// XCD-disjoint f mapping: xcd=id&7; g=id>>3; mb=xcd*4+(g&3); nb=g>>2.
// Swizzle: 8 slots/row, slot ^= row&7 (involution; 2-way read = free).
// ---------------------------------------------------------------------------
#define GBM 128
#define GBN 64
#define GBK 64

__global__ __launch_bounds__(256, 3) void gemm_argmin_mfma(
    const u16* __restrict__ f_hi, const u16* __restrict__ f_lo,
    const u16* __restrict__ c_hi, const u16* __restrict__ c_lo,
    const float* __restrict__ c2, unsigned long long* __restrict__ packed)
{
    __shared__ __align__(16) u16 Ah[GBM * GBK];   // 16 KB
    __shared__ __align__(16) u16 Al[GBM * GBK];   // 16 KB
    __shared__ __align__(16) u16 Bh[GBN * GBK];   // 8 KB
    __shared__ __align__(16) u16 Bl[GBN * GBK];   // 8 KB
    __shared__ unsigned long long red[GBM];

    const int tid = threadIdx.x;
    const int id = blockIdx.x;
    const int xcd = id & 7;
    const int g = id >> 3;
    const int mb = xcd * 4 + (g & 3);   // 4 disjoint m-panels per XCD
    const int nb = g >> 2;              // all 16 n-panels per XCD
    const int m0 = mb * GBM;
    const int n0 = nb * GBN;

    const int lane = tid & 63;
    const int wid  = tid >> 6;
    const int wm = wid >> 1, wn = wid & 1;
    const int li = lane & 15;
    const int ls = lane >> 4;

    if (tid < GBM) red[tid] = ~0ULL;

    f32x4 acc[4][2];
    #pragma unroll
    for (int i = 0; i < 4; ++i)
        #pragma unroll
        for (int j = 0; j < 2; ++j) acc[i][j] = (f32x4){0.f, 0.f, 0.f, 0.f};

    for (int k0 = 0; k0 < 4096; k0 += GBK) {
        // stage A: 128 rows x 64 k (1024 16B-chunks per plane), swizzled source
        #pragma unroll
        for (int q = 0; q < 4; ++q) {
            int idx = tid + q * 256;          // 0..1023
            int row = idx >> 3, slot = idx & 7;
            int kg = k0 + ((slot ^ (row & 7)) << 3);
            size_t goff = (size_t)(m0 + row) * 4096 + kg;
            load_lds16(f_hi + goff, &Ah[idx * 8]);
            load_lds16(f_lo + goff, &Al[idx * 8]);
        }
        // stage B: 64 rows x 64 k (512 chunks per plane)
        #pragma unroll
        for (int q = 0; q < 2; ++q) {
            int idx = tid + q * 256;          // 0..511
            int row = idx >> 3, slot = idx & 7;
            int kg = k0 + ((slot ^ (row & 7)) << 3);
            size_t goff = (size_t)(n0 + row) * 4096 + kg;
            load_lds16(c_hi + goff, &Bh[idx * 8]);
            load_lds16(c_lo + goff, &Bl[idx * 8]);
        }
        __syncthreads();   // drains vmcnt -> tile resident

        #pragma unroll
        for (int ks = 0; ks < 2; ++ks) {      // two K=32 sub-steps
            const int c = ks * 4 + ls;        // global 16B k-chunk index
            bf16x8 ah[4], al[4], bh[2], bl[2];
            #pragma unroll
            for (int mt = 0; mt < 4; ++mt) {
                int r = wm * 64 + mt * 16 + li;
                int byte = r * 128 + ((c ^ (r & 7)) << 4);
                ah[mt] = *(const bf16x8*)((const char*)Ah + byte);
                al[mt] = *(const bf16x8*)((const char*)Al + byte);
            }
            #pragma unroll
            for (int nt = 0; nt < 2; ++nt) {
                int r = wn * 32 + nt * 16 + li;
                int byte = r * 128 + ((c ^ (r & 7)) << 4);
                bh[nt] = *(const bf16x8*)((const char*)Bh + byte);
                bl[nt] = *(const bf16x8*)((const char*)Bl + byte);
            }
            #pragma unroll
            for (int mt = 0; mt < 4; ++mt)
                #pragma unroll
                for (int nt = 0; nt < 2; ++nt) {
                    acc[mt][nt] = __builtin_amdgcn_mfma_f32_16x16x32_bf16(ah[mt], bh[nt], acc[mt][nt], 0, 0, 0);
                    acc[mt][nt] = __builtin_amdgcn_mfma_f32_16x16x32_bf16(ah[mt], bl[nt], acc[mt][nt], 0, 0, 0);
                    acc[mt][nt] = __builtin_amdgcn_mfma_f32_16x16x32_bf16(al[mt], bh[nt], acc[mt][nt], 0, 0, 0);
                }
        }
        __syncthreads();   // before next-tile overwrite
    }

    // epilogue: argmin of (c2[n] - 2*dot). C/D: col=lane&15, row=(lane>>4)*4+reg.
    #pragma unroll
    for (int mt = 0; mt < 4; ++mt) {
        #pragma unroll
        for (int reg = 0; reg < 4; ++reg) {
            unsigned long long best = ~0ULL;
            #pragma unroll
            for (int nt = 0; nt < 2; ++nt) {
                int n = n0 + wn * 32 + nt * 16 + li;
                if (n < 1000) {
                    float v = c2[n] - 2.0f * acc[mt][nt][reg];
                    unsigned bi = __float_as_uint(v);
                    bi = (bi & 0x80000000u) ? ~bi : (bi | 0x80000000u);
                    unsigned long long key = ((unsigned long long)bi << 32) | (unsigned)n;
                    if (key < best) best = key;
                }
            }
            #pragma unroll
            for (int d = 1; d < 16; d <<= 1) {
                unsigned long long o = __shfl_xor(best, d, 64);
                if (o < best) best = o;
            }
            if (li == 0) {
                int lr = wm * 64 + mt * 16 + ls * 4 + reg;
                atomicMin(&red[lr], best);
            }
        }
    }
    __syncthreads();
    if (tid < GBM) atomicMin(&packed[m0 + tid], red[tid]);
}

// ---------------------------------------------------------------------------
// Kernel 3: unpack argmin index
// ---------------------------------------------------------------------------
__global__ __launch_bounds__(256) void extract_kernel(
    const unsigned long long* __restrict__ packed, int* __restrict__ out)
{
    int i = blockIdx.x * 256 + threadIdx.x;
    out[i] = (int)(unsigned)(packed[i] & 0xFFFFFFFFull);
}

// ---------------------------------------------------------------------------
extern "C" void kernel_launch(void* const* d_in, const int* in_sizes, int n_in,
                              void* d_out, int out_size, void* d_ws, size_t ws_size,
                              hipStream_t stream)
{
    const float* x    = (const float*)d_in[0];
    const float* w1   = (const float*)d_in[1];
    const float* b1   = (const float*)d_in[2];
    const float* w2   = (const float*)d_in[3];
    const float* b2   = (const float*)d_in[4];
    const float* cent = (const float*)d_in[5];
    int* out = (int*)d_out;

    char* ws = (char*)d_ws;
    u16* f_hi = (u16*)(ws);                          // 4096*4096*2 = 33554432
    u16* f_lo = (u16*)(ws + 33554432);               // 33554432
    u16* c_hi = (u16*)(ws + 67108864);               // 1024*4096*2 = 8388608
    u16* c_lo = (u16*)(ws + 75497472);               // 8388608
    float* c2 = (float*)(ws + 83886080);             // 4096
    unsigned long long* packed =
        (unsigned long long*)(ws + 83890176);        // 32768
    u16* w1t = (u16*)(ws + 83922944);                // 4096
    u16* w2t = (u16*)(ws + 83927040);                // 73728 (dedicated)

    prep_w_kernel<<<168, 256, 0, stream>>>(w1, w2, w1t, w2t, packed);
    conv_fused_kernel<<<5096, 256, 0, stream>>>(x, w1t, b1, w2t, b2, f_hi, f_lo,
                                                cent, c_hi, c_lo, c2);
    gemm_argmin_mfma<<<512, 256, 0, stream>>>(f_hi, f_lo, c_hi, c_lo, c2, packed);
    extract_kernel<<<16, 256, 0, stream>>>(packed, out);
}